// Round 2
// baseline (117.839 us; speedup 1.0000x reference)
//
#include <hip/hip_runtime.h>
#include <math.h>

// WayfinderAttention: B=1, H=16, T=2048, DH=64, D=64 neighbors. f32 in/out.
// R12: THEORY PIVOT — drop the workspace entirely.
//   Rocprof showed top-5 dispatches are 256 MiB fillBufferAligned (~45 us each,
//   75% HBM peak) = harness re-poisoning d_ws each iteration; our attn kernel
//   is ABSENT from top-5 => attn kernel itself < 44 us. Measured 112 us ~=
//   ws-poison (45) + convert prepass (~5) + attn (~43) + overhead.
//   Using d_ws is what drags the poison fill into the timed path.
// Delta: single kernel, NO d_ws use, NO convert prepass. f32 gathers directly
//   from k/v with R10's phase structure:
//     - compaction of valid neighbors (ballot/popc) into LDS
//     - score: entry e <- 8 lanes (c8 dims), 8-deep K-row prefetch (2x float4)
//     - wave softmax over compacted entries (lane = entry)
//     - PV: quarter qw x 4 entries, 16 lanes x float4 per V row, full 16-row
//       prefetch before consumption, f32 accumulate
//   Numerics now pure f32 (absmax should drop 0.0156 -> ~1e-6).
// Prediction: dur_us 112 -> ~75-90 if poison was timed; ~125-140 if not
//   (falsifies theory -> revert to f16+ws next round).

#define T_DIM 2048
#define DH    64
#define NB    64
#define WPB   4

__global__ __launch_bounds__(WPB * 64)
void wayfinder_attn(const float* __restrict__ q,
                    const float* __restrict__ k,
                    const float* __restrict__ v,
                    const float* __restrict__ etb,
                    const int*   __restrict__ neigh_idx,
                    const int*   __restrict__ edge_type,
                    float*       __restrict__ out)
{
    __shared__ int   j_s[WPB][NB];
    __shared__ float b_s[WPB][NB];
    __shared__ float w_s[WPB][NB];
    __shared__ float dot_s[WPB][NB];

    const int lane = threadIdx.x & 63;
    const int wave = threadIdx.x >> 6;
    const int wq   = blockIdx.x * WPB + wave;     // flat h*T + t (B=1)
    const int t    = wq & (T_DIM - 1);
    const int qbase    = wq * DH;                 // floats, < 2^21
    const int headbase = (wq - t) * DH;           // floats
    const float* __restrict__ kh = k + headbase;
    const float* __restrict__ vh = v + headbase;

    // init padding (entries >= nv read as row 0 / bias 0 / weight 0)
    j_s[wave][lane] = 0;
    b_s[wave][lane] = 0.f;

    // per-lane neighbor metadata (lane d owns raw neighbor slot d)
    const int raw = neigh_idx[wq * NB + lane];
    const int et  = edge_type[wq * NB + lane];
    const bool valid = (raw >= 0) && (raw <= t);
    const int  sj    = min(max(raw, 0), T_DIM - 1);
    const float bias = (et != 0) ? etb[et - 1] : 0.f;

    // compaction: valid entries -> positions [0, nv)
    const unsigned long long vb = __ballot(valid);
    const int nv  = __popcll(vb);
    const int pos = __popcll(vb & ((1ull << lane) - 1ull));
    if (valid) { j_s[wave][pos] = sj; b_s[wave][pos] = bias; }

    // ---- score phase: iteration i covers entries i*8..i*8+7; group g8
    //      handles entry e = i*8+g8; lane covers dims 8*c8..8*c8+7.
    //      Guard i*8<nv is wave-uniform. ----
    const int c8 = lane & 7;
    const int g8 = lane >> 3;
    const float4 qv0 = *(const float4*)(q + qbase + c8 * 8);
    const float4 qv1 = *(const float4*)(q + qbase + c8 * 8 + 4);

    // prefetch: up to 16 independent dwordx4 loads in flight
    float4 kr0[8], kr1[8];
    #pragma unroll
    for (int i = 0; i < 8; ++i) {
        if (i * 8 < nv) {
            const int je = j_s[wave][i * 8 + g8];   // entries >= nv -> row 0 (safe)
            kr0[i] = *(const float4*)(kh + je * DH + c8 * 8);
            kr1[i] = *(const float4*)(kh + je * DH + c8 * 8 + 4);
        }
    }

    #pragma unroll
    for (int i = 0; i < 8; ++i) {
        if (i * 8 < nv) {
            float p = kr0[i].x * qv0.x + kr0[i].y * qv0.y
                    + kr0[i].z * qv0.z + kr0[i].w * qv0.w
                    + kr1[i].x * qv1.x + kr1[i].y * qv1.y
                    + kr1[i].z * qv1.z + kr1[i].w * qv1.w;
            p += __shfl_xor(p, 1, 64);
            p += __shfl_xor(p, 2, 64);
            p += __shfl_xor(p, 4, 64);
            if (c8 == 0) dot_s[wave][i * 8 + g8] = p;   // capture entry e
        }
    }
    const float mydot = dot_s[wave][lane];   // entry 'lane' (garbage if >= nv)

    // ---- softmax over compacted entries (lane d = entry d) ----
    const bool dval = lane < nv;
    const float score = dval ? (mydot * 0.125f + b_s[wave][lane]) : -INFINITY;
    float m = score;
    #pragma unroll
    for (int o = 32; o > 0; o >>= 1) m = fmaxf(m, __shfl_xor(m, o, 64));
    const float e = dval ? __expf(score - m) : 0.f;
    float s = e;
    #pragma unroll
    for (int o = 32; o > 0; o >>= 1) s += __shfl_xor(s, o, 64);
    const float w = e / fmaxf(s, 1e-20f);
    w_s[wave][lane] = w;   // entries >= nv get w=0 (padding-safe)

    // ---- PV: quarter qw takes contiguous entries i*16+qw*4..+3; 16 lanes x
    //      float4 (16B) per V row; all rows prefetched, then f32 accumulate ----
    const int qw   = lane >> 4;      // quarter 0..3
    const int lp16 = lane & 15;      // dims 4*lp16..4*lp16+3
    float4 vr[16];
    #pragma unroll
    for (int i = 0; i < 4; ++i) {
        if (i * 16 < nv) {
            const int4 jd = *(const int4*)&j_s[wave][i * 16 + qw * 4];
            vr[i * 4 + 0] = *(const float4*)(vh + jd.x * DH + lp16 * 4);
            vr[i * 4 + 1] = *(const float4*)(vh + jd.y * DH + lp16 * 4);
            vr[i * 4 + 2] = *(const float4*)(vh + jd.z * DH + lp16 * 4);
            vr[i * 4 + 3] = *(const float4*)(vh + jd.w * DH + lp16 * 4);
        }
    }
    float a0 = 0.f, a1 = 0.f, a2 = 0.f, a3 = 0.f;
    #pragma unroll
    for (int i = 0; i < 4; ++i) {
        if (i * 16 < nv) {
            const float4 wd = *(const float4*)&w_s[wave][i * 16 + qw * 4];
            a0 += wd.x * vr[i * 4 + 0].x;  a1 += wd.x * vr[i * 4 + 0].y;
            a2 += wd.x * vr[i * 4 + 0].z;  a3 += wd.x * vr[i * 4 + 0].w;
            a0 += wd.y * vr[i * 4 + 1].x;  a1 += wd.y * vr[i * 4 + 1].y;
            a2 += wd.y * vr[i * 4 + 1].z;  a3 += wd.y * vr[i * 4 + 1].w;
            a0 += wd.z * vr[i * 4 + 2].x;  a1 += wd.z * vr[i * 4 + 2].y;
            a2 += wd.z * vr[i * 4 + 2].z;  a3 += wd.z * vr[i * 4 + 2].w;
            a0 += wd.w * vr[i * 4 + 3].x;  a1 += wd.w * vr[i * 4 + 3].y;
            a2 += wd.w * vr[i * 4 + 3].z;  a3 += wd.w * vr[i * 4 + 3].w;
        }
    }
    // reduce across quarters (butterfly), then lanes 0..15 store float4
    a0 += __shfl_xor(a0, 16, 64);  a1 += __shfl_xor(a1, 16, 64);
    a2 += __shfl_xor(a2, 16, 64);  a3 += __shfl_xor(a3, 16, 64);
    a0 += __shfl_xor(a0, 32, 64);  a1 += __shfl_xor(a1, 32, 64);
    a2 += __shfl_xor(a2, 32, 64);  a3 += __shfl_xor(a3, 32, 64);
    if (lane < 16) {
        float4 o; o.x = a0; o.y = a1; o.z = a2; o.w = a3;
        *(float4*)(out + qbase + lane * 4) = o;
    }
}

extern "C" void kernel_launch(void* const* d_in, const int* in_sizes, int n_in,
                              void* d_out, int out_size, void* d_ws, size_t ws_size,
                              hipStream_t stream)
{
    const float* q   = (const float*)d_in[0];
    const float* k   = (const float*)d_in[1];
    const float* v   = (const float*)d_in[2];
    const float* etb = (const float*)d_in[3];
    const int* neigh_idx = (const int*)d_in[4];
    const int* edge_type = (const int*)d_in[5];
    float* out = (float*)d_out;

    (void)d_ws; (void)ws_size;   // deliberately unused: avoid ws re-poison cost

    const int total_queries = 16 * T_DIM;     // 32768
    const int blocks = total_queries / WPB;   // 8192
    hipLaunchKernelGGL(wayfinder_attn, dim3(blocks), dim3(WPB * 64),
                       0, stream, q, k, v, etb, neigh_idx, edge_type, out);
}

// Round 3
// 114.733 us; speedup vs baseline: 1.0271x; 1.0271x over previous
//
#include <hip/hip_runtime.h>
#include <math.h>

// WayfinderAttention: B=1, H=16, T=2048, DH=64, D=64 neighbors. f32 in/out.
// R13: R12 (f32 no-ws, attn kernel 44-48us, VALUBusy 35%, HBM 21%, FETCH 69.6MB
//      vs 40MB ideal => latency-bound on L2-missing gathers) + SINGLE DELTA:
//      XCD-aware blockIdx swizzle (T1). Grid 8192 = 16 heads x 512 blocks;
//      default round-robin puts all 16 heads' K/V (16 MB) in every XCD's 4MB
//      L2 -> gathers miss to HBM (~900cy). Swizzle swz=(bid&7)*1024+(bid>>3)
//      gives each XCD 2 contiguous heads = 2MB working set < 4MB L2 ->
//      gathers become L2 hits (~200cy).
// Prediction: kernel FETCH 69.6->~45MB, kernel dur 46->~32-38us,
//      total dur 117.8 -> ~103-108.

#define T_DIM 2048
#define DH    64
#define NB    64
#define WPB   4

__global__ __launch_bounds__(WPB * 64)
void wayfinder_attn(const float* __restrict__ q,
                    const float* __restrict__ k,
                    const float* __restrict__ v,
                    const float* __restrict__ etb,
                    const int*   __restrict__ neigh_idx,
                    const int*   __restrict__ edge_type,
                    float*       __restrict__ out)
{
    __shared__ int   j_s[WPB][NB];
    __shared__ float b_s[WPB][NB];
    __shared__ float w_s[WPB][NB];
    __shared__ float dot_s[WPB][NB];

    const int lane = threadIdx.x & 63;
    const int wave = threadIdx.x >> 6;

    // ---- R13 delta: XCD-aware swizzle. 8192 blocks, 8 XCDs, 1024 each.
    //      XCD x (= bid%8 under round-robin dispatch) covers contiguous
    //      block range [x*1024, (x+1)*1024) = 2 heads of K/V (2 MB, L2-fit).
    const int bid = blockIdx.x;
    const int swz = (bid & 7) * 1024 + (bid >> 3);

    const int wq   = swz * WPB + wave;            // flat h*T + t (B=1)
    const int t    = wq & (T_DIM - 1);
    const int qbase    = wq * DH;                 // floats, < 2^21
    const int headbase = (wq - t) * DH;           // floats
    const float* __restrict__ kh = k + headbase;
    const float* __restrict__ vh = v + headbase;

    // init padding (entries >= nv read as row 0 / bias 0 / weight 0)
    j_s[wave][lane] = 0;
    b_s[wave][lane] = 0.f;

    // per-lane neighbor metadata (lane d owns raw neighbor slot d)
    const int raw = neigh_idx[wq * NB + lane];
    const int et  = edge_type[wq * NB + lane];
    const bool valid = (raw >= 0) && (raw <= t);
    const int  sj    = min(max(raw, 0), T_DIM - 1);
    const float bias = (et != 0) ? etb[et - 1] : 0.f;

    // compaction: valid entries -> positions [0, nv)
    const unsigned long long vb = __ballot(valid);
    const int nv  = __popcll(vb);
    const int pos = __popcll(vb & ((1ull << lane) - 1ull));
    if (valid) { j_s[wave][pos] = sj; b_s[wave][pos] = bias; }

    // ---- score phase: iteration i covers entries i*8..i*8+7; group g8
    //      handles entry e = i*8+g8; lane covers dims 8*c8..8*c8+7.
    //      Guard i*8<nv is wave-uniform. ----
    const int c8 = lane & 7;
    const int g8 = lane >> 3;
    const float4 qv0 = *(const float4*)(q + qbase + c8 * 8);
    const float4 qv1 = *(const float4*)(q + qbase + c8 * 8 + 4);

    // prefetch: up to 16 independent dwordx4 loads in flight
    float4 kr0[8], kr1[8];
    #pragma unroll
    for (int i = 0; i < 8; ++i) {
        if (i * 8 < nv) {
            const int je = j_s[wave][i * 8 + g8];   // entries >= nv -> row 0 (safe)
            kr0[i] = *(const float4*)(kh + je * DH + c8 * 8);
            kr1[i] = *(const float4*)(kh + je * DH + c8 * 8 + 4);
        }
    }

    #pragma unroll
    for (int i = 0; i < 8; ++i) {
        if (i * 8 < nv) {
            float p = kr0[i].x * qv0.x + kr0[i].y * qv0.y
                    + kr0[i].z * qv0.z + kr0[i].w * qv0.w
                    + kr1[i].x * qv1.x + kr1[i].y * qv1.y
                    + kr1[i].z * qv1.z + kr1[i].w * qv1.w;
            p += __shfl_xor(p, 1, 64);
            p += __shfl_xor(p, 2, 64);
            p += __shfl_xor(p, 4, 64);
            if (c8 == 0) dot_s[wave][i * 8 + g8] = p;   // capture entry e
        }
    }
    const float mydot = dot_s[wave][lane];   // entry 'lane' (garbage if >= nv)

    // ---- softmax over compacted entries (lane d = entry d) ----
    const bool dval = lane < nv;
    const float score = dval ? (mydot * 0.125f + b_s[wave][lane]) : -INFINITY;
    float m = score;
    #pragma unroll
    for (int o = 32; o > 0; o >>= 1) m = fmaxf(m, __shfl_xor(m, o, 64));
    const float e = dval ? __expf(score - m) : 0.f;
    float s = e;
    #pragma unroll
    for (int o = 32; o > 0; o >>= 1) s += __shfl_xor(s, o, 64);
    const float w = e / fmaxf(s, 1e-20f);
    w_s[wave][lane] = w;   // entries >= nv get w=0 (padding-safe)

    // ---- PV: quarter qw takes contiguous entries i*16+qw*4..+3; 16 lanes x
    //      float4 (16B) per V row; all rows prefetched, then f32 accumulate ----
    const int qw   = lane >> 4;      // quarter 0..3
    const int lp16 = lane & 15;      // dims 4*lp16..4*lp16+3
    float4 vr[16];
    #pragma unroll
    for (int i = 0; i < 4; ++i) {
        if (i * 16 < nv) {
            const int4 jd = *(const int4*)&j_s[wave][i * 16 + qw * 4];
            vr[i * 4 + 0] = *(const float4*)(vh + jd.x * DH + lp16 * 4);
            vr[i * 4 + 1] = *(const float4*)(vh + jd.y * DH + lp16 * 4);
            vr[i * 4 + 2] = *(const float4*)(vh + jd.z * DH + lp16 * 4);
            vr[i * 4 + 3] = *(const float4*)(vh + jd.w * DH + lp16 * 4);
        }
    }
    float a0 = 0.f, a1 = 0.f, a2 = 0.f, a3 = 0.f;
    #pragma unroll
    for (int i = 0; i < 4; ++i) {
        if (i * 16 < nv) {
            const float4 wd = *(const float4*)&w_s[wave][i * 16 + qw * 4];
            a0 += wd.x * vr[i * 4 + 0].x;  a1 += wd.x * vr[i * 4 + 0].y;
            a2 += wd.x * vr[i * 4 + 0].z;  a3 += wd.x * vr[i * 4 + 0].w;
            a0 += wd.y * vr[i * 4 + 1].x;  a1 += wd.y * vr[i * 4 + 1].y;
            a2 += wd.y * vr[i * 4 + 1].z;  a3 += wd.y * vr[i * 4 + 1].w;
            a0 += wd.z * vr[i * 4 + 2].x;  a1 += wd.z * vr[i * 4 + 2].y;
            a2 += wd.z * vr[i * 4 + 2].z;  a3 += wd.z * vr[i * 4 + 2].w;
            a0 += wd.w * vr[i * 4 + 3].x;  a1 += wd.w * vr[i * 4 + 3].y;
            a2 += wd.w * vr[i * 4 + 3].z;  a3 += wd.w * vr[i * 4 + 3].w;
        }
    }
    // reduce across quarters (butterfly), then lanes 0..15 store float4
    a0 += __shfl_xor(a0, 16, 64);  a1 += __shfl_xor(a1, 16, 64);
    a2 += __shfl_xor(a2, 16, 64);  a3 += __shfl_xor(a3, 16, 64);
    a0 += __shfl_xor(a0, 32, 64);  a1 += __shfl_xor(a1, 32, 64);
    a2 += __shfl_xor(a2, 32, 64);  a3 += __shfl_xor(a3, 32, 64);
    if (lane < 16) {
        float4 o; o.x = a0; o.y = a1; o.z = a2; o.w = a3;
        *(float4*)(out + qbase + lane * 4) = o;
    }
}

extern "C" void kernel_launch(void* const* d_in, const int* in_sizes, int n_in,
                              void* d_out, int out_size, void* d_ws, size_t ws_size,
                              hipStream_t stream)
{
    const float* q   = (const float*)d_in[0];
    const float* k   = (const float*)d_in[1];
    const float* v   = (const float*)d_in[2];
    const float* etb = (const float*)d_in[3];
    const int* neigh_idx = (const int*)d_in[4];
    const int* edge_type = (const int*)d_in[5];
    float* out = (float*)d_out;

    (void)d_ws; (void)ws_size;   // deliberately unused: avoid ws re-poison cost

    const int total_queries = 16 * T_DIM;     // 32768
    const int blocks = total_queries / WPB;   // 8192
    hipLaunchKernelGGL(wayfinder_attn, dim3(blocks), dim3(WPB * 64),
                       0, stream, q, k, v, etb, neigh_idx, edge_type, out);
}